// Round 1
// baseline (132.897 us; speedup 1.0000x reference)
//
#include <hip/hip_runtime.h>

#define EPS 1e-5f

__device__ __forceinline__ float fsigm(float x) { return 1.0f / (1.0f + __expf(-x)); }
__device__ __forceinline__ float ftanh(float x) {
    float e = __expf(-2.0f * x);
    return (1.0f - e) / (1.0f + e);
}

// ---------------------------------------------------------------------------
// Kernel 1: per-frame frontend (MLP 63->63->64 + LayerNorm) and input-side
// gate projection Gx[t] = f_t @ w_ih.T + b_ih + b_hh.  No cross-frame
// dependence -> one block (one wave) per frame, 60 blocks.
// All weights staged in LDS; w_ih staged TRANSPOSED so the gate matvec reads
// wihT[k*128 + j] (bank = j%32, conflict-free).
// ---------------------------------------------------------------------------
__global__ __launch_bounds__(64) void frontend_kernel(
    const float* __restrict__ x,                                     // [60,63]
    const float* __restrict__ w00, const float* __restrict__ b00,    // [63,63],[63]
    const float* __restrict__ w01, const float* __restrict__ b01,    // [64,63],[64]
    const float* __restrict__ ln_g, const float* __restrict__ ln_b,  // [64],[64]
    const float* __restrict__ w_ih,                                  // [128,64]
    const float* __restrict__ b_ih, const float* __restrict__ b_hh,  // [128],[128]
    float* __restrict__ Gx)                                          // [60,128]
{
    // 3972 + 4032 + 8192 + 128 = 16324 floats = 65,296 B (<= 64 KiB)
    __shared__ float smem[16324];
    float* w00s = smem;          // [63*63] rows stride 63 (bank-conflict-free)
    float* w01s = smem + 3972;   // [64*63]
    float* wihT = smem + 8004;   // [64][128] transposed w_ih
    float* scr  = smem + 16196;  // [128] activations scratch

    const int j = threadIdx.x;
    const int t = blockIdx.x;

    // --- stage w00 (3969 floats = 992 float4 + 1 tail) ---
    {
        const float4* g4 = (const float4*)w00;
        float4* s4 = (float4*)w00s;
        for (int i = j; i < 992; i += 64) s4[i] = g4[i];
        if (j == 0) w00s[3968] = w00[3968];
    }
    // --- stage w01 (4032 floats = 1008 float4) ---
    {
        const float4* g4 = (const float4*)w01;
        float4* s4 = (float4*)w01s;
        for (int i = j; i < 1008; i += 64) s4[i] = g4[i];
    }
    // --- stage w_ih transposed: wihT[k*128 + r] = w_ih[r*64 + k] ---
    for (int r = j; r < 128; r += 64) {
        const float4* row = (const float4*)(w_ih + r * 64);
        #pragma unroll
        for (int q = 0; q < 16; q++) {
            float4 v = row[q];
            wihT[(4 * q + 0) * 128 + r] = v.x;
            wihT[(4 * q + 1) * 128 + r] = v.y;
            wihT[(4 * q + 2) * 128 + r] = v.z;
            wihT[(4 * q + 3) * 128 + r] = v.w;
        }
    }
    // --- load x_t ---
    scr[j] = (j < 63) ? x[t * 63 + j] : 0.0f;
    __syncthreads();

    // --- stage 1: f0 = relu(x @ w00.T + b00), 63 outputs ---
    float f0 = 0.0f;
    if (j < 63) {
        float acc = b00[j];
        const float* wr = w00s + j * 63;
        #pragma unroll
        for (int k = 0; k < 63; k++) acc += scr[k] * wr[k];
        f0 = fmaxf(acc, 0.0f);
    }
    __syncthreads();
    scr[j] = f0;  // lane 63 writes 0
    __syncthreads();

    // --- stage 2: f1 = relu(f0 @ w01.T + b01), 64 outputs ---
    float acc = b01[j];
    {
        const float* wr = w01s + j * 63;
        #pragma unroll
        for (int k = 0; k < 63; k++) acc += scr[k] * wr[k];
    }
    float f1 = fmaxf(acc, 0.0f);

    // --- LayerNorm over the 64 lanes (wave butterfly reduce) ---
    float s = f1, sq = f1 * f1;
    #pragma unroll
    for (int off = 32; off > 0; off >>= 1) {
        s  += __shfl_xor(s, off);
        sq += __shfl_xor(sq, off);
    }
    float mu  = s * (1.0f / 64.0f);
    float var = sq * (1.0f / 64.0f) - mu * mu;
    float f   = (f1 - mu) * rsqrtf(var + EPS) * ln_g[j] + ln_b[j];
    __syncthreads();
    scr[64 + j] = f;
    __syncthreads();

    // --- gate projection: rows j and j+64 of w_ih ---
    float a0 = b_ih[j] + b_hh[j];
    float a1 = b_ih[j + 64] + b_hh[j + 64];
    #pragma unroll
    for (int k = 0; k < 64; k++) {
        float fk = scr[64 + k];
        a0 += fk * wihT[k * 128 + j];
        a1 += fk * wihT[k * 128 + 64 + j];
    }
    Gx[t * 128 + j]      = a0;
    Gx[t * 128 + 64 + j] = a1;
}

// ---------------------------------------------------------------------------
// Kernel 2: sequential LSTM scan (single wave) + output head.
// Lane j owns gate rows j and j+64: for j<32 that is (i_j, g_j), for j=32+m
// it is (f_m, o_m); the cross pair comes via __shfl_xor(.,32).
// w_hh rows live in 64 VGPRs per lane; h is broadcast through LDS as 8
// float4 reads (same-address broadcast, conflict-free).
// ---------------------------------------------------------------------------
__global__ __launch_bounds__(64) void scan_kernel(
    const float* __restrict__ Gx,                                    // [60,128]
    const float* __restrict__ w_hh,                                  // [128,32]
    const float* __restrict__ bn_g, const float* __restrict__ bn_b,  // [32],[32]
    const float* __restrict__ w10, const float* __restrict__ b10,    // [32,32],[32]
    const float* __restrict__ w11, const float* __restrict__ b11,    // [32,32],[32]
    const float* __restrict__ w12, const float* __restrict__ b12,    // [256,32],[256]
    float* __restrict__ out)                                         // [256]
{
    __shared__ float gxs[7680];  // 60*128
    __shared__ float hs[32];
    __shared__ float hbs[32];
    __shared__ float os1[32];
    __shared__ float os2[32];
    const int j = threadIdx.x;

    // --- stage Gx into LDS (1920 float4s) ---
    {
        const float4* g4 = (const float4*)Gx;
        float4* s4 = (float4*)gxs;
        for (int i = j; i < 1920; i += 64) s4[i] = g4[i];
    }
    // --- w_hh rows j and j+64 into registers ---
    float wA[32], wB[32];
    {
        const float4* r0 = (const float4*)(w_hh + j * 32);
        const float4* r1 = (const float4*)(w_hh + (j + 64) * 32);
        #pragma unroll
        for (int q = 0; q < 8; q++) {
            float4 a = r0[q];
            float4 b = r1[q];
            wA[4 * q] = a.x; wA[4 * q + 1] = a.y; wA[4 * q + 2] = a.z; wA[4 * q + 3] = a.w;
            wB[4 * q] = b.x; wB[4 * q + 1] = b.y; wB[4 * q + 2] = b.z; wB[4 * q + 3] = b.w;
        }
    }
    float hv[32];
    #pragma unroll
    for (int k = 0; k < 32; k++) hv[k] = 0.0f;
    float c = 0.0f;
    __syncthreads();

    for (int t = 0; t < 60; t++) {
        // gates: split accumulators into 4 chains so the loop is issue-bound
        float a0a = gxs[t * 128 + j],      a0b = 0.0f;
        float a1a = gxs[t * 128 + 64 + j], a1b = 0.0f;
        #pragma unroll
        for (int k = 0; k < 16; k++) {
            a0a += hv[k] * wA[k];
            a1a += hv[k] * wB[k];
        }
        #pragma unroll
        for (int k = 16; k < 32; k++) {
            a0b += hv[k] * wA[k];
            a1b += hv[k] * wB[k];
        }
        float a0 = a0a + a0b;  // j<32: i_j ; j>=32: f_{j-32}
        float a1 = a1a + a1b;  // j<32: g_j ; j>=32: o_{j-32}
        float fv = __shfl_xor(a0, 32);
        float ov = __shfl_xor(a1, 32);
        // only lanes <32 hold meaningful state; others compute harmless junk
        c = fsigm(fv) * c + fsigm(a0) * ftanh(a1);
        float hn = fsigm(ov) * ftanh(c);
        if (j < 32) hs[j] = hn;
        __syncthreads();
        #pragma unroll
        for (int q = 0; q < 8; q++) {
            float4 v = ((const float4*)hs)[q];
            hv[4 * q] = v.x; hv[4 * q + 1] = v.y; hv[4 * q + 2] = v.z; hv[4 * q + 3] = v.w;
        }
        __syncthreads();
    }

    // --- head: BN(eval) -> 32x32 relu -> 32x32 relu -> 256x32 ---
    const float rs = rsqrtf(1.0f + EPS);
    if (j < 32) hbs[j] = hs[j] * rs * bn_g[j] + bn_b[j];
    __syncthreads();
    if (j < 32) {
        float acc = b10[j];
        const float* wr = w10 + j * 32;
        #pragma unroll
        for (int k = 0; k < 32; k++) acc += wr[k] * hbs[k];
        os1[j] = fmaxf(acc, 0.0f);
    }
    __syncthreads();
    if (j < 32) {
        float acc = b11[j];
        const float* wr = w11 + j * 32;
        #pragma unroll
        for (int k = 0; k < 32; k++) acc += wr[k] * os1[k];
        os2[j] = fmaxf(acc, 0.0f);
    }
    __syncthreads();
    #pragma unroll
    for (int r = 0; r < 4; r++) {
        int o = j + 64 * r;
        float acc = b12[o];
        const float* wr = w12 + o * 32;
        #pragma unroll
        for (int k = 0; k < 32; k++) acc += wr[k] * os2[k];
        out[o] = acc;
    }
}

extern "C" void kernel_launch(void* const* d_in, const int* in_sizes, int n_in,
                              void* d_out, int out_size, void* d_ws, size_t ws_size,
                              hipStream_t stream) {
    const float* x    = (const float*)d_in[0];
    const float* w00  = (const float*)d_in[1];
    const float* b00  = (const float*)d_in[2];
    const float* w01  = (const float*)d_in[3];
    const float* b01  = (const float*)d_in[4];
    const float* ln_g = (const float*)d_in[5];
    const float* ln_b = (const float*)d_in[6];
    const float* w_ih = (const float*)d_in[7];
    const float* w_hh = (const float*)d_in[8];
    const float* b_ih = (const float*)d_in[9];
    const float* b_hh = (const float*)d_in[10];
    const float* bn_g = (const float*)d_in[11];
    const float* bn_b = (const float*)d_in[12];
    const float* w10  = (const float*)d_in[13];
    const float* b10  = (const float*)d_in[14];
    const float* w11  = (const float*)d_in[15];
    const float* b11  = (const float*)d_in[16];
    const float* w12  = (const float*)d_in[17];
    const float* b12  = (const float*)d_in[18];
    float* out = (float*)d_out;
    float* Gx  = (float*)d_ws;  // 60*128*4 = 30,720 B

    frontend_kernel<<<60, 64, 0, stream>>>(x, w00, b00, w01, b01, ln_g, ln_b,
                                           w_ih, b_ih, b_hh, Gx);
    scan_kernel<<<1, 64, 0, stream>>>(Gx, w_hh, bn_g, bn_b, w10, b10, w11, b11,
                                      w12, b12, out);
}